// Round 11
// baseline (2488.913 us; speedup 1.0000x reference)
//
#include <hip/hip_runtime.h>
#include <stdint.h>

#define TT 128
#define BB 128
#define OBSD 512
#define HID 1024
#define DPAR 24

typedef _Float16 f16;
typedef _Float16 f16x8 __attribute__((ext_vector_type(8)));
typedef float f32x4 __attribute__((ext_vector_type(4)));

__device__ __forceinline__ f32x4 mfma16(f16x8 a, f16x8 b, f32x4 c){
  return __builtin_amdgcn_mfma_f32_16x16x32_f16(a, b, c, 0, 0, 0);
}

// ---- prep: world_state f32 -> f16 ----
__global__ void k_ws_to_f16(const float* __restrict__ src, f16* __restrict__ dst, int n4){
  int i = blockIdx.x * blockDim.x + threadIdx.x;
  if (i < n4){
    float4 v = *reinterpret_cast<const float4*>(src + (size_t)i * 4);
    dst[(size_t)i*4 + 0] = (f16)v.x; dst[(size_t)i*4 + 1] = (f16)v.y;
    dst[(size_t)i*4 + 2] = (f16)v.z; dst[(size_t)i*4 + 3] = (f16)v.w;
  }
}

// ---- prep: transpose f32 [KD][C] (row stride srcStride) -> f16 dst[C][KD] ----
__global__ void k_prep_bt(const float* __restrict__ s0, int srcStride,
                          f16* __restrict__ dst, int KD){
  __shared__ f16 sm[64][65];
  int k0 = blockIdx.x * 64, c0 = blockIdx.y * 64;
  for (int it = 0; it < 16; ++it){
    int idx = it * 256 + threadIdx.x;
    int kr = idx >> 6, cc = idx & 63;
    sm[kr][cc] = (f16)s0[(size_t)(k0 + kr) * srcStride + (c0 + cc)];
  }
  __syncthreads();
  for (int it = 0; it < 16; ++it){
    int idx = it * 256 + threadIdx.x;
    int cr = idx >> 6, kc = idx & 63;
    dst[(size_t)(c0 + cr) * KD + (k0 + kc)] = sm[kc][cr];
  }
}

// ---- prep: bt2[c][k] = k<1024 ? Wi[k][c] : Wh[k-1024][c]; c<3072, k<2048 ----
__global__ void k_prep_bt2(const float* __restrict__ wi, const float* __restrict__ wh,
                           f16* __restrict__ dst){
  __shared__ f16 sm[64][65];
  int k0 = blockIdx.x * 64, c0 = blockIdx.y * 64;
  const float* src = (k0 < 1024) ? wi : wh;
  int kb = (k0 < 1024) ? k0 : k0 - 1024;
  for (int it = 0; it < 16; ++it){
    int idx = it * 256 + threadIdx.x;
    int kr = idx >> 6, cc = idx & 63;
    sm[kr][cc] = (f16)src[(size_t)(kb + kr) * 3072 + (c0 + cc)];
  }
  __syncthreads();
  for (int it = 0; it < 16; ++it){
    int idx = it * 256 + threadIdx.x;
    int cr = idx >> 6, kc = idx & 63;
    dst[(size_t)(c0 + cr) * 2048 + (k0 + kc)] = sm[kc][cr];
  }
}

// ---- segmentation: bucket (t,b) rows by chain depth; record long chains ----
__global__ void k_seg(const int* __restrict__ dones, int* __restrict__ off,
                      int* __restrict__ rowlist, int* __restrict__ ntail,
                      int* __restrict__ chains){
  __shared__ int cnt[DPAR];
  __shared__ int cur[DPAR];
  int tid = threadIdx.x;               // 128 threads, one per b
  if (tid < DPAR) cnt[tid] = 0;
  if (tid == 0) *ntail = 0;
  __syncthreads();
  int b = tid;
  int start = 0;
  for (int t = 1; t <= TT; ++t){
    bool boundary = (t == TT) || (dones[t * BB + b] != 0);
    if (boundary){
      int len = t - start;
      int nb = len < DPAR ? len : DPAR;
      for (int d = 0; d < nb; ++d) atomicAdd(&cnt[d], 1);
      if (len > DPAR){
        int c = atomicAdd(ntail, 1);
        chains[c*3+0] = b; chains[c*3+1] = start; chains[c*3+2] = len;
      }
      start = t;
    }
  }
  __syncthreads();
  if (tid == 0){
    int s = 0;
    for (int d = 0; d < DPAR; ++d){ off[d] = s; cur[d] = s; s += cnt[d]; }
    off[DPAR] = s;
  }
  __syncthreads();
  start = 0;
  for (int t = 1; t <= TT; ++t){
    bool boundary = (t == TT) || (dones[t * BB + b] != 0);
    if (boundary){
      int len = t - start;
      int nb = len < DPAR ? len : DPAR;
      for (int d = 0; d < nb; ++d){
        int pos = atomicAdd(&cur[d], 1);
        rowlist[pos] = ((start + d) << 7) | b;
      }
      start = t;
    }
  }
}

// ---- emb = relu(ws @ W_emb + b_emb): [16384x512]@[512->1024], f16 out ----
__global__ __launch_bounds__(256)
void k_emb(const f16* __restrict__ A, const f16* __restrict__ Bt,
           const float* __restrict__ bias, f16* __restrict__ outb){
  int w = threadIdx.x >> 6, lane = threadIdx.x & 63;
  int wm = w >> 1, wn = w & 1;
  int bid = blockIdx.x;                       // 1024 = 128 Mb x 8 Nb
  int vid = (bid & 7) * 128 + (bid >> 3);
  int Mb = (vid >> 3) * 128, Nb = (vid & 7) * 128;
  int la = lane & 15, lk = (lane >> 4) * 8;
  f32x4 acc[4][4] = {};
  const f16* Ap[4]; const f16* Bp[4];
  for (int i = 0; i < 4; ++i){
    Ap[i] = A + (size_t)(Mb + wm*64 + i*16 + la) * OBSD;
    Bp[i] = Bt + (size_t)(Nb + wn*64 + i*16 + la) * OBSD;
  }
  for (int k = 0; k < OBSD; k += 32){
    f16x8 af[4], bfr[4];
    for (int i = 0; i < 4; ++i){
      af[i]  = *reinterpret_cast<const f16x8*>(Ap[i] + k + lk);
      bfr[i] = *reinterpret_cast<const f16x8*>(Bp[i] + k + lk);
    }
    for (int mi = 0; mi < 4; ++mi)
      for (int ni = 0; ni < 4; ++ni)
        acc[mi][ni] = mfma16(af[mi], bfr[ni], acc[mi][ni]);
  }
  for (int mi = 0; mi < 4; ++mi) for (int ni = 0; ni < 4; ++ni){
    int col = Nb + wn*64 + ni*16 + la;
    float bb = bias[col];
    for (int i = 0; i < 4; ++i){
      int row = Mb + wm*64 + mi*16 + (lane >> 4)*4 + i;
      float v = acc[mi][ni][i] + bb;
      outb[(size_t)row * HID + col] = (f16)(v > 0.f ? v : 0.f);
    }
  }
}

// ---- depth-j fused GRU step: [emb | h_prev] @ [Wi; Wh], K=2048 ----
// BM=128 gathered rows x BN=192 (64 hcols x 3 gates). 512 thr = 2m x 4n waves.
// A staged per K-tile (128x256 f16 = 64KB LDS, XOR swizzle, conflict-free);
// B direct from L2 (nb%8 XCD-pinned, 1.57MB/XCD). Full-K acc in registers.
// grid 1024 = 64 M-strides x 16 nb.
__global__ __launch_bounds__(512, 4)
void k_depth(int j, const int* __restrict__ off, const int* __restrict__ rowlist,
             const f16* __restrict__ emb, const f16* __restrict__ bt2,
             const float* __restrict__ bi_p, const float* __restrict__ bhn_p,
             const int* __restrict__ dones, const float* __restrict__ hidden0,
             f16* __restrict__ y, float* __restrict__ hout){
  __shared__ __attribute__((aligned(16))) char smem[65536];   // 128 x 256 f16
  const int base = off[j];
  const int count = off[j+1] - base;
  if (count <= 0) return;
  const int tid = threadIdx.x;
  const int lane = tid & 63;
  const int w = tid >> 6;                    // 8 waves
  const int wm = w >> 2, wn = w & 3;         // 2m x 4n
  const int nb = blockIdx.x & 15;
  const int st = blockIdx.x >> 4;            // 64 M-strides
  const int la = lane & 15, lk = (lane >> 4) * 8;
  const int hcolw = nb*64 + wn*16;           // wave's hcol base
  const f16* Bg0 = bt2 + (size_t)(          hcolw + la) * 2048 + lk;
  const f16* Bg1 = bt2 + (size_t)(1024 +    hcolw + la) * 2048 + lk;
  const f16* Bg2 = bt2 + (size_t)(2048 +    hcolw + la) * 2048 + lk;
  const int ntiles = (count + 127) >> 7;

  for (int tile = st; tile < ntiles; tile += 64){
    f32x4 ar[4] = {}, az[4] = {}, axn[4] = {}, ahn[4] = {};
    #pragma unroll
    for (int ph = 0; ph < 2; ++ph){
      #pragma unroll 1
      for (int kt = 0; kt < 4; ++kt){
        __syncthreads();                     // prev GEMM/epilogue done with smem
        // ---- stage 128 rows x 256 K: 8 x 16B per thread (4096 slots = 64KB) ----
        #pragma unroll
        for (int q = 0; q < 8; ++q){
          int idx = tid + q*512;
          int r = idx >> 5, c = idx & 31;    // row [0,128), 16B slot [0,32)
          int ridx = tile*128 + r;
          int tb = (ridx < count) ? rowlist[base + ridx] : -1;
          int ko = kt*256 + c*8;
          float4 v = {0.f, 0.f, 0.f, 0.f};
          if (tb >= 0){
            int t = tb >> 7, b = tb & 127;
            if (ph == 0){
              v = *reinterpret_cast<const float4*>(emb + ((size_t)t*BB + b)*HID + ko);
            } else if (j > 0){
              v = *reinterpret_cast<const float4*>(y + ((size_t)(t-1)*BB + b)*HID + ko);
            } else if (t == 0 && dones[b] == 0){
              const float* s = hidden0 + (size_t)b*HID + ko;
              float4 a0 = *reinterpret_cast<const float4*>(s);
              float4 a1 = *reinterpret_cast<const float4*>(s + 4);
              f16 h8[8] = {(f16)a0.x,(f16)a0.y,(f16)a0.z,(f16)a0.w,
                           (f16)a1.x,(f16)a1.y,(f16)a1.z,(f16)a1.w};
              v = *reinterpret_cast<float4*>(h8);
            }
          }
          int byte = (r*512 + c*16) ^ ((r & 7) << 4);
          *reinterpret_cast<float4*>(smem + byte) = v;
        }
        __syncthreads();
        // ---- GEMM on this K-tile: 4 m-frags x 3 gates per wave per kk ----
        const int kbase = ph*1024 + kt*256;
        #pragma unroll
        for (int kk = 0; kk < 256; kk += 32){
          f16x8 av[4];
          #pragma unroll
          for (int m = 0; m < 4; ++m){
            int r = wm*64 + m*16 + la;
            av[m] = *reinterpret_cast<const f16x8*>(
                smem + ((r*512 + (kk + lk)*2) ^ ((r & 7) << 4)));
          }
          f16x8 b0 = *reinterpret_cast<const f16x8*>(Bg0 + kbase + kk);
          f16x8 b1 = *reinterpret_cast<const f16x8*>(Bg1 + kbase + kk);
          f16x8 b2 = *reinterpret_cast<const f16x8*>(Bg2 + kbase + kk);
          #pragma unroll
          for (int m = 0; m < 4; ++m){
            ar[m] = mfma16(av[m], b0, ar[m]);
            az[m] = mfma16(av[m], b1, az[m]);
            if (ph == 0) axn[m] = mfma16(av[m], b2, axn[m]);
            else         ahn[m] = mfma16(av[m], b2, ahn[m]);
          }
        }
      }
    }
    // ---- epilogue: 16 outputs/thread direct from registers ----
    {
      int hcol = hcolw + la;
      float bir = bi_p[hcol], biz = bi_p[HID + hcol], bin = bi_p[2*HID + hcol];
      float bh = bhn_p[hcol];
      #pragma unroll
      for (int m = 0; m < 4; ++m){
        #pragma unroll
        for (int i = 0; i < 4; ++i){
          int lr = wm*64 + m*16 + (lane >> 4)*4 + i;
          int ridx = tile*128 + lr;
          if (ridx >= count) continue;
          int tb = rowlist[base + ridx];
          int t = tb >> 7, b = tb & 127;
          float hold;
          if (j > 0) hold = (float)y[((size_t)(t-1)*BB + b)*HID + hcol];
          else if (t == 0 && dones[b] == 0) hold = hidden0[(size_t)b*HID + hcol];
          else hold = 0.f;
          float r = 1.f / (1.f + expf(-(ar[m][i] + bir)));
          float z = 1.f / (1.f + expf(-(az[m][i] + biz)));
          float n = tanhf(axn[m][i] + bin + r * (ahn[m][i] + bh));
          float hnew = (1.f - z) * n + z * hold;
          y[((size_t)t*BB + b)*HID + hcol] = (f16)hnew;
          if (t == TT - 1) hout[(size_t)b*HID + hcol] = hnew;
        }
      }
    }
  }
}

// ---- sequential tail for chains longer than DPAR (expected: none) ----
__global__ __launch_bounds__(256)
void k_tail(const int* __restrict__ ntail, const int* __restrict__ chains,
            const f16* __restrict__ emb, const f16* __restrict__ bt2,
            const float* __restrict__ bi_p, const float* __restrict__ bhn_p,
            f16* __restrict__ y, float* __restrict__ hout){
  int n = *ntail;
  __shared__ f16 hs[1024];
  __shared__ f16 es[1024];
  int tid = threadIdx.x;
  for (int c = blockIdx.x; c < n; c += gridDim.x){
    int b = chains[c*3], t0 = chains[c*3+1], len = chains[c*3+2];
    for (int i = tid; i < 1024; i += 256)
      hs[i] = y[((size_t)(t0 + DPAR - 1)*BB + b)*HID + i];
    __syncthreads();
    for (int t = t0 + DPAR; t < t0 + len; ++t){
      for (int i = tid; i < 1024; i += 256)
        es[i] = emb[((size_t)t*BB + b)*HID + i];
      __syncthreads();
      float tmp[4];
      #pragma unroll
      for (int u = 0; u < 4; ++u){
        int col = tid*4 + u;
        float s_r = 0.f, s_z = 0.f, s_xn = 0.f, s_hn = 0.f;
        const f16* wr = bt2 + (size_t)col*2048;
        const f16* wz = bt2 + (size_t)(1024+col)*2048;
        const f16* wn = bt2 + (size_t)(2048+col)*2048;
        for (int q = 0; q < 128; ++q){
          f16x8 ev = *reinterpret_cast<const f16x8*>(&es[q*8]);
          f16x8 hv = *reinterpret_cast<const f16x8*>(&hs[q*8]);
          f16x8 wre = *reinterpret_cast<const f16x8*>(wr + q*8);
          f16x8 wrh = *reinterpret_cast<const f16x8*>(wr + 1024 + q*8);
          f16x8 wze = *reinterpret_cast<const f16x8*>(wz + q*8);
          f16x8 wzh = *reinterpret_cast<const f16x8*>(wz + 1024 + q*8);
          f16x8 wne = *reinterpret_cast<const f16x8*>(wn + q*8);
          f16x8 wnh = *reinterpret_cast<const f16x8*>(wn + 1024 + q*8);
          #pragma unroll
          for (int e = 0; e < 8; ++e){
            float ee = (float)ev[e], hh = (float)hv[e];
            s_r  += ee*(float)wre[e] + hh*(float)wrh[e];
            s_z  += ee*(float)wze[e] + hh*(float)wzh[e];
            s_xn += ee*(float)wne[e];
            s_hn += hh*(float)wnh[e];
          }
        }
        float r = 1.f / (1.f + expf(-(s_r + bi_p[col])));
        float z = 1.f / (1.f + expf(-(s_z + bi_p[1024+col])));
        float nn = tanhf(s_xn + bi_p[2048+col] + r * (s_hn + bhn_p[col]));
        float hold = (float)hs[col];
        float hnew = (1.f - z) * nn + z * hold;
        y[((size_t)t*BB + b)*HID + col] = (f16)hnew;
        if (t == TT - 1) hout[(size_t)b*HID + col] = hnew;
        tmp[u] = hnew;
      }
      __syncthreads();
      #pragma unroll
      for (int u = 0; u < 4; ++u) hs[tid*4 + u] = (f16)tmp[u];
      __syncthreads();
    }
    __syncthreads();
  }
}

// ---- critic fused with value partials: 128x128 tile, K=1024, f16 ----
__global__ __launch_bounds__(256)
void k_critic(const f16* __restrict__ Y, const f16* __restrict__ Bt,
              const float* __restrict__ b1, const float* __restrict__ W2,
              float* __restrict__ vpart){
  int w = threadIdx.x >> 6, lane = threadIdx.x & 63;
  int wm = w >> 1, wn = w & 1;
  int bid = blockIdx.x;
  int vid = (bid & 7) * 128 + (bid >> 3);
  int Mb = (vid >> 3) * 128, Nb = (vid & 7) * 128;
  int la = lane & 15, lk = (lane >> 4) * 8;
  f32x4 acc[4][4] = {};
  const f16* Ap[4]; const f16* Bp[4];
  for (int i = 0; i < 4; ++i){
    Ap[i] = Y  + (size_t)(Mb + wm*64 + i*16 + la) * HID;
    Bp[i] = Bt + (size_t)(Nb + wn*64 + i*16 + la) * HID;
  }
  #pragma unroll 2
  for (int k = 0; k < HID; k += 32){
    f16x8 af[4], bfr[4];
    for (int i = 0; i < 4; ++i){
      af[i]  = *reinterpret_cast<const f16x8*>(Ap[i] + k + lk);
      bfr[i] = *reinterpret_cast<const f16x8*>(Bp[i] + k + lk);
    }
    for (int mi = 0; mi < 4; ++mi)
      for (int ni = 0; ni < 4; ++ni)
        acc[mi][ni] = mfma16(af[mi], bfr[ni], acc[mi][ni]);
  }
  __shared__ float vs[2][64][2];
  float p[4][4];
  for (int mi = 0; mi < 4; ++mi) for (int i = 0; i < 4; ++i) p[mi][i] = 0.f;
  for (int ni = 0; ni < 4; ++ni){
    int col = Nb + wn*64 + ni*16 + la;
    float bb = b1[col], w2 = W2[col];
    for (int mi = 0; mi < 4; ++mi)
      for (int i = 0; i < 4; ++i){
        float c = acc[mi][ni][i] + bb;
        p[mi][i] += (c > 0.f ? c : 0.f) * w2;
      }
  }
  for (int mi = 0; mi < 4; ++mi) for (int i = 0; i < 4; ++i){
    float s = p[mi][i];
    s += __shfl_xor(s, 1); s += __shfl_xor(s, 2);
    s += __shfl_xor(s, 4); s += __shfl_xor(s, 8);
    p[mi][i] = s;
  }
  if (la == 0){
    int q = lane >> 4;
    for (int mi = 0; mi < 4; ++mi)
      for (int i = 0; i < 4; ++i)
        vs[wm][mi*16 + q*4 + i][wn] = p[mi][i];
  }
  __syncthreads();
  if (threadIdx.x < 128){
    int rw = threadIdx.x;
    float s = vs[rw >> 6][rw & 63][0] + vs[rw >> 6][rw & 63][1];
    vpart[(size_t)(Nb >> 7) * (TT*BB) + Mb + rw] = s;
  }
}

__global__ void k_vreduce(const float* __restrict__ vpart, const float* __restrict__ b2,
                          float* __restrict__ outv){
  int m = blockIdx.x * 256 + threadIdx.x;
  float s = b2[0];
  for (int nb = 0; nb < 8; ++nb) s += vpart[(size_t)nb * (TT*BB) + m];
  outv[m] = s;
}

extern "C" void kernel_launch(void* const* d_in, const int* in_sizes, int n_in,
                              void* d_out, int out_size, void* d_ws, size_t ws_size,
                              hipStream_t stream){
  const float* hidden = (const float*)d_in[0];
  const float* world  = (const float*)d_in[1];
  const int*   dones  = (const int*)d_in[2];
  const float* W_emb  = (const float*)d_in[3];
  const float* b_emb  = (const float*)d_in[4];
  const float* Wi     = (const float*)d_in[5];
  const float* bi     = (const float*)d_in[6];
  const float* Wh     = (const float*)d_in[7];
  const float* bhn    = (const float*)d_in[8];
  const float* W1     = (const float*)d_in[9];
  const float* b1     = (const float*)d_in[10];
  const float* W2     = (const float*)d_in[11];
  const float* b2     = (const float*)d_in[12];
  float* out = (float*)d_out;

  char* p = (char*)d_ws;
  auto alloc = [&](size_t bytes) -> char* {
    char* r = p; p += (bytes + 255) & ~(size_t)255; return r;
  };
  f16*   ws16   = (f16*)alloc((size_t)TT*BB*OBSD*2);     // 16 MB
  f16*   wembt  = (f16*)alloc((size_t)HID*OBSD*2);       // 1 MB
  f16*   emb16  = (f16*)alloc((size_t)TT*BB*HID*2);      // 33.5 MB
  f16*   bt2    = (f16*)alloc((size_t)3072*2048*2);      // 12.6 MB
  f16*   w1t    = (f16*)alloc((size_t)HID*HID*2);        // 2 MB
  f16*   ybuf   = (f16*)alloc((size_t)TT*BB*HID*2);      // 33.5 MB
  float* vpart  = (float*)alloc((size_t)8*TT*BB*4);      // 0.5 MB
  int*   off    = (int*)alloc((DPAR + 1) * 4);
  int*   rowlist= (int*)alloc((size_t)(TT*BB + 128)*4);  // 64 KB (+pad)
  int*   ntail  = (int*)alloc(4);
  int*   chains = (int*)alloc((size_t)700*3*4);
  if ((size_t)(p - (char*)d_ws) > ws_size) return;

  // preps (+ segmentation, depends only on dones)
  k_ws_to_f16<<<(TT*BB*OBSD/4 + 255)/256, 256, 0, stream>>>(world, ws16, TT*BB*OBSD/4);
  k_prep_bt<<<dim3(OBSD/64, HID/64), 256, 0, stream>>>(W_emb, 1024, wembt, OBSD);
  k_prep_bt2<<<dim3(2048/64, 3072/64), 256, 0, stream>>>(Wi, Wh, bt2);
  k_prep_bt<<<dim3(HID/64, HID/64), 256, 0, stream>>>(W1, 1024, w1t, HID);
  k_seg<<<1, 128, 0, stream>>>(dones, off, rowlist, ntail, chains);

  // embedding GEMM
  k_emb<<<1024, 256, 0, stream>>>(ws16, wembt, b_emb, emb16);

  // depth-parallel fused GRU scan: 24 launches + tail
  for (int j = 0; j < DPAR; ++j)
    k_depth<<<1024, 512, 0, stream>>>(j, off, rowlist, emb16, bt2, bi, bhn,
                                      dones, hidden, ybuf, out);
  k_tail<<<128, 256, 0, stream>>>(ntail, chains, emb16, bt2, bi, bhn, ybuf, out);

  // critic head + value
  k_critic<<<1024, 256, 0, stream>>>(ybuf, w1t, b1, W2, vpart);
  k_vreduce<<<TT*BB/256, 256, 0, stream>>>(vpart, b2, out + (size_t)BB*HID);
}

// Round 12
// 1997.259 us; speedup vs baseline: 1.2462x; 1.2462x over previous
//
#include <hip/hip_runtime.h>
#include <stdint.h>

#define TT 128
#define BB 128
#define OBSD 512
#define HID 1024
#define DPAR 24

typedef _Float16 f16;
typedef _Float16 f16x8 __attribute__((ext_vector_type(8)));
typedef float f32x4 __attribute__((ext_vector_type(4)));

__device__ __forceinline__ f32x4 mfma16(f16x8 a, f16x8 b, f32x4 c){
  return __builtin_amdgcn_mfma_f32_16x16x32_f16(a, b, c, 0, 0, 0);
}

// ---- prep: world_state f32 -> f16 ----
__global__ void k_ws_to_f16(const float* __restrict__ src, f16* __restrict__ dst, int n4){
  int i = blockIdx.x * blockDim.x + threadIdx.x;
  if (i < n4){
    float4 v = *reinterpret_cast<const float4*>(src + (size_t)i * 4);
    dst[(size_t)i*4 + 0] = (f16)v.x; dst[(size_t)i*4 + 1] = (f16)v.y;
    dst[(size_t)i*4 + 2] = (f16)v.z; dst[(size_t)i*4 + 3] = (f16)v.w;
  }
}

// ---- prep: transpose f32 [KD][C] (row stride srcStride) -> f16 dst[C][KD] ----
__global__ void k_prep_bt(const float* __restrict__ s0, int srcStride,
                          f16* __restrict__ dst, int KD){
  __shared__ f16 sm[64][65];
  int k0 = blockIdx.x * 64, c0 = blockIdx.y * 64;
  for (int it = 0; it < 16; ++it){
    int idx = it * 256 + threadIdx.x;
    int kr = idx >> 6, cc = idx & 63;
    sm[kr][cc] = (f16)s0[(size_t)(k0 + kr) * srcStride + (c0 + cc)];
  }
  __syncthreads();
  for (int it = 0; it < 16; ++it){
    int idx = it * 256 + threadIdx.x;
    int cr = idx >> 6, kc = idx & 63;
    dst[(size_t)(c0 + cr) * KD + (k0 + kc)] = sm[kc][cr];
  }
}

// ---- prep: bt2[c][k] = k<1024 ? Wi[k][c] : Wh[k-1024][c]; c<3072, k<2048 ----
__global__ void k_prep_bt2(const float* __restrict__ wi, const float* __restrict__ wh,
                           f16* __restrict__ dst){
  __shared__ f16 sm[64][65];
  int k0 = blockIdx.x * 64, c0 = blockIdx.y * 64;
  const float* src = (k0 < 1024) ? wi : wh;
  int kb = (k0 < 1024) ? k0 : k0 - 1024;
  for (int it = 0; it < 16; ++it){
    int idx = it * 256 + threadIdx.x;
    int kr = idx >> 6, cc = idx & 63;
    sm[kr][cc] = (f16)src[(size_t)(kb + kr) * 3072 + (c0 + cc)];
  }
  __syncthreads();
  for (int it = 0; it < 16; ++it){
    int idx = it * 256 + threadIdx.x;
    int cr = idx >> 6, kc = idx & 63;
    dst[(size_t)(c0 + cr) * 2048 + (k0 + kc)] = sm[kc][cr];
  }
}

// ---- segmentation: bucket (t,b) rows by chain depth; record long chains ----
__global__ void k_seg(const int* __restrict__ dones, int* __restrict__ off,
                      int* __restrict__ rowlist, int* __restrict__ ntail,
                      int* __restrict__ chains){
  __shared__ int cnt[DPAR];
  __shared__ int cur[DPAR];
  int tid = threadIdx.x;               // 128 threads, one per b
  if (tid < DPAR) cnt[tid] = 0;
  if (tid == 0) *ntail = 0;
  __syncthreads();
  int b = tid;
  int start = 0;
  for (int t = 1; t <= TT; ++t){
    bool boundary = (t == TT) || (dones[t * BB + b] != 0);
    if (boundary){
      int len = t - start;
      int nb = len < DPAR ? len : DPAR;
      for (int d = 0; d < nb; ++d) atomicAdd(&cnt[d], 1);
      if (len > DPAR){
        int c = atomicAdd(ntail, 1);
        chains[c*3+0] = b; chains[c*3+1] = start; chains[c*3+2] = len;
      }
      start = t;
    }
  }
  __syncthreads();
  if (tid == 0){
    int s = 0;
    for (int d = 0; d < DPAR; ++d){ off[d] = s; cur[d] = s; s += cnt[d]; }
    off[DPAR] = s;
  }
  __syncthreads();
  start = 0;
  for (int t = 1; t <= TT; ++t){
    bool boundary = (t == TT) || (dones[t * BB + b] != 0);
    if (boundary){
      int len = t - start;
      int nb = len < DPAR ? len : DPAR;
      for (int d = 0; d < nb; ++d){
        int pos = atomicAdd(&cur[d], 1);
        rowlist[pos] = ((start + d) << 7) | b;
      }
      start = t;
    }
  }
}

// ---- emb = relu(ws @ W_emb + b_emb): [16384x512]@[512->1024], f16 out ----
__global__ __launch_bounds__(256)
void k_emb(const f16* __restrict__ A, const f16* __restrict__ Bt,
           const float* __restrict__ bias, f16* __restrict__ outb){
  int w = threadIdx.x >> 6, lane = threadIdx.x & 63;
  int wm = w >> 1, wn = w & 1;
  int bid = blockIdx.x;                       // 1024 = 128 Mb x 8 Nb
  int vid = (bid & 7) * 128 + (bid >> 3);
  int Mb = (vid >> 3) * 128, Nb = (vid & 7) * 128;
  int la = lane & 15, lk = (lane >> 4) * 8;
  f32x4 acc[4][4] = {};
  const f16* Ap[4]; const f16* Bp[4];
  for (int i = 0; i < 4; ++i){
    Ap[i] = A + (size_t)(Mb + wm*64 + i*16 + la) * OBSD;
    Bp[i] = Bt + (size_t)(Nb + wn*64 + i*16 + la) * OBSD;
  }
  for (int k = 0; k < OBSD; k += 32){
    f16x8 af[4], bfr[4];
    for (int i = 0; i < 4; ++i){
      af[i]  = *reinterpret_cast<const f16x8*>(Ap[i] + k + lk);
      bfr[i] = *reinterpret_cast<const f16x8*>(Bp[i] + k + lk);
    }
    for (int mi = 0; mi < 4; ++mi)
      for (int ni = 0; ni < 4; ++ni)
        acc[mi][ni] = mfma16(af[mi], bfr[ni], acc[mi][ni]);
  }
  for (int mi = 0; mi < 4; ++mi) for (int ni = 0; ni < 4; ++ni){
    int col = Nb + wn*64 + ni*16 + la;
    float bb = bias[col];
    for (int i = 0; i < 4; ++i){
      int row = Mb + wm*64 + mi*16 + (lane >> 4)*4 + i;
      float v = acc[mi][ni][i] + bb;
      outb[(size_t)row * HID + col] = (f16)(v > 0.f ? v : 0.f);
    }
  }
}

// ---- depth-j fused GRU step: [emb | h_prev] @ [Wi; Wh], K=2048 ----
// BM=128 gathered rows x BN=192 (64 hcols x 3 gates). 512 thr = 2m x 4n waves.
// A staged per K-tile (128x256 f16 = 64KB LDS, XOR swizzle);
// B direct from L2 (nb%8 XCD-pinned). Full-K acc in registers (64 VGPR acc).
// grid 1024 = 64 M-strides x 16 nb. NOTE: no min-waves clamp -> no spills.
__global__ __launch_bounds__(512)
void k_depth(int j, const int* __restrict__ off, const int* __restrict__ rowlist,
             const f16* __restrict__ emb, const f16* __restrict__ bt2,
             const float* __restrict__ bi_p, const float* __restrict__ bhn_p,
             const int* __restrict__ dones, const float* __restrict__ hidden0,
             f16* __restrict__ y, float* __restrict__ hout){
  __shared__ __attribute__((aligned(16))) char smem[65536];   // 128 x 256 f16
  const int base = off[j];
  const int count = off[j+1] - base;
  if (count <= 0) return;
  const int tid = threadIdx.x;
  const int lane = tid & 63;
  const int w = tid >> 6;                    // 8 waves
  const int wm = w >> 2, wn = w & 3;         // 2m x 4n
  const int nb = blockIdx.x & 15;
  const int st = blockIdx.x >> 4;            // 64 M-strides
  const int la = lane & 15, lk = (lane >> 4) * 8;
  const int hcolw = nb*64 + wn*16;           // wave's hcol base
  const f16* Bg0 = bt2 + (size_t)(          hcolw + la) * 2048 + lk;
  const f16* Bg1 = bt2 + (size_t)(1024 +    hcolw + la) * 2048 + lk;
  const f16* Bg2 = bt2 + (size_t)(2048 +    hcolw + la) * 2048 + lk;
  const int ntiles = (count + 127) >> 7;

  for (int tile = st; tile < ntiles; tile += 64){
    f32x4 ar[4] = {}, az[4] = {}, axn[4] = {}, ahn[4] = {};
    #pragma unroll
    for (int ph = 0; ph < 2; ++ph){
      #pragma unroll 1
      for (int kt = 0; kt < 4; ++kt){
        __syncthreads();                     // prev GEMM/epilogue done with smem
        // ---- stage 128 rows x 256 K: 8 x 16B per thread (4096 slots = 64KB) ----
        #pragma unroll
        for (int q = 0; q < 8; ++q){
          int idx = tid + q*512;
          int r = idx >> 5, c = idx & 31;    // row [0,128), 16B slot [0,32)
          int ridx = tile*128 + r;
          int tb = (ridx < count) ? rowlist[base + ridx] : -1;
          int ko = kt*256 + c*8;
          float4 v = {0.f, 0.f, 0.f, 0.f};
          if (tb >= 0){
            int t = tb >> 7, b = tb & 127;
            if (ph == 0){
              v = *reinterpret_cast<const float4*>(emb + ((size_t)t*BB + b)*HID + ko);
            } else if (j > 0){
              v = *reinterpret_cast<const float4*>(y + ((size_t)(t-1)*BB + b)*HID + ko);
            } else if (t == 0 && dones[b] == 0){
              const float* s = hidden0 + (size_t)b*HID + ko;
              float4 a0 = *reinterpret_cast<const float4*>(s);
              float4 a1 = *reinterpret_cast<const float4*>(s + 4);
              f16 h8[8] = {(f16)a0.x,(f16)a0.y,(f16)a0.z,(f16)a0.w,
                           (f16)a1.x,(f16)a1.y,(f16)a1.z,(f16)a1.w};
              v = *reinterpret_cast<float4*>(h8);
            }
          }
          int byte = (r*512 + c*16) ^ ((r & 7) << 4);
          *reinterpret_cast<float4*>(smem + byte) = v;
        }
        __syncthreads();
        // ---- GEMM on this K-tile: 4 m-frags x 3 gates per wave per kk ----
        const int kbase = ph*1024 + kt*256;
        #pragma unroll
        for (int kk = 0; kk < 256; kk += 32){
          f16x8 av[4];
          #pragma unroll
          for (int m = 0; m < 4; ++m){
            int r = wm*64 + m*16 + la;
            av[m] = *reinterpret_cast<const f16x8*>(
                smem + ((r*512 + (kk + lk)*2) ^ ((r & 7) << 4)));
          }
          f16x8 b0 = *reinterpret_cast<const f16x8*>(Bg0 + kbase + kk);
          f16x8 b1 = *reinterpret_cast<const f16x8*>(Bg1 + kbase + kk);
          f16x8 b2 = *reinterpret_cast<const f16x8*>(Bg2 + kbase + kk);
          #pragma unroll
          for (int m = 0; m < 4; ++m){
            ar[m] = mfma16(av[m], b0, ar[m]);
            az[m] = mfma16(av[m], b1, az[m]);
            if (ph == 0) axn[m] = mfma16(av[m], b2, axn[m]);
            else         ahn[m] = mfma16(av[m], b2, ahn[m]);
          }
        }
      }
    }
    // ---- epilogue: 16 outputs/thread direct from registers ----
    {
      int hcol = hcolw + la;
      float bir = bi_p[hcol], biz = bi_p[HID + hcol], bin = bi_p[2*HID + hcol];
      float bh = bhn_p[hcol];
      #pragma unroll
      for (int m = 0; m < 4; ++m){
        #pragma unroll
        for (int i = 0; i < 4; ++i){
          int lr = wm*64 + m*16 + (lane >> 4)*4 + i;
          int ridx = tile*128 + lr;
          if (ridx >= count) continue;
          int tb = rowlist[base + ridx];
          int t = tb >> 7, b = tb & 127;
          float hold;
          if (j > 0) hold = (float)y[((size_t)(t-1)*BB + b)*HID + hcol];
          else if (t == 0 && dones[b] == 0) hold = hidden0[(size_t)b*HID + hcol];
          else hold = 0.f;
          float r = 1.f / (1.f + expf(-(ar[m][i] + bir)));
          float z = 1.f / (1.f + expf(-(az[m][i] + biz)));
          float n = tanhf(axn[m][i] + bin + r * (ahn[m][i] + bh));
          float hnew = (1.f - z) * n + z * hold;
          y[((size_t)t*BB + b)*HID + hcol] = (f16)hnew;
          if (t == TT - 1) hout[(size_t)b*HID + hcol] = hnew;
        }
      }
    }
  }
}

// ---- sequential tail for chains longer than DPAR (expected: none) ----
__global__ __launch_bounds__(256)
void k_tail(const int* __restrict__ ntail, const int* __restrict__ chains,
            const f16* __restrict__ emb, const f16* __restrict__ bt2,
            const float* __restrict__ bi_p, const float* __restrict__ bhn_p,
            f16* __restrict__ y, float* __restrict__ hout){
  int n = *ntail;
  __shared__ f16 hs[1024];
  __shared__ f16 es[1024];
  int tid = threadIdx.x;
  for (int c = blockIdx.x; c < n; c += gridDim.x){
    int b = chains[c*3], t0 = chains[c*3+1], len = chains[c*3+2];
    for (int i = tid; i < 1024; i += 256)
      hs[i] = y[((size_t)(t0 + DPAR - 1)*BB + b)*HID + i];
    __syncthreads();
    for (int t = t0 + DPAR; t < t0 + len; ++t){
      for (int i = tid; i < 1024; i += 256)
        es[i] = emb[((size_t)t*BB + b)*HID + i];
      __syncthreads();
      float tmp[4];
      #pragma unroll
      for (int u = 0; u < 4; ++u){
        int col = tid*4 + u;
        float s_r = 0.f, s_z = 0.f, s_xn = 0.f, s_hn = 0.f;
        const f16* wr = bt2 + (size_t)col*2048;
        const f16* wz = bt2 + (size_t)(1024+col)*2048;
        const f16* wn = bt2 + (size_t)(2048+col)*2048;
        for (int q = 0; q < 128; ++q){
          f16x8 ev = *reinterpret_cast<const f16x8*>(&es[q*8]);
          f16x8 hv = *reinterpret_cast<const f16x8*>(&hs[q*8]);
          f16x8 wre = *reinterpret_cast<const f16x8*>(wr + q*8);
          f16x8 wrh = *reinterpret_cast<const f16x8*>(wr + 1024 + q*8);
          f16x8 wze = *reinterpret_cast<const f16x8*>(wz + q*8);
          f16x8 wzh = *reinterpret_cast<const f16x8*>(wz + 1024 + q*8);
          f16x8 wne = *reinterpret_cast<const f16x8*>(wn + q*8);
          f16x8 wnh = *reinterpret_cast<const f16x8*>(wn + 1024 + q*8);
          #pragma unroll
          for (int e = 0; e < 8; ++e){
            float ee = (float)ev[e], hh = (float)hv[e];
            s_r  += ee*(float)wre[e] + hh*(float)wrh[e];
            s_z  += ee*(float)wze[e] + hh*(float)wzh[e];
            s_xn += ee*(float)wne[e];
            s_hn += hh*(float)wnh[e];
          }
        }
        float r = 1.f / (1.f + expf(-(s_r + bi_p[col])));
        float z = 1.f / (1.f + expf(-(s_z + bi_p[1024+col])));
        float nn = tanhf(s_xn + bi_p[2048+col] + r * (s_hn + bhn_p[col]));
        float hold = (float)hs[col];
        float hnew = (1.f - z) * nn + z * hold;
        y[((size_t)t*BB + b)*HID + col] = (f16)hnew;
        if (t == TT - 1) hout[(size_t)b*HID + col] = hnew;
        tmp[u] = hnew;
      }
      __syncthreads();
      #pragma unroll
      for (int u = 0; u < 4; ++u) hs[tid*4 + u] = (f16)tmp[u];
      __syncthreads();
    }
    __syncthreads();
  }
}

// ---- critic fused with value partials: 128x128 tile, K=1024, f16 ----
__global__ __launch_bounds__(256)
void k_critic(const f16* __restrict__ Y, const f16* __restrict__ Bt,
              const float* __restrict__ b1, const float* __restrict__ W2,
              float* __restrict__ vpart){
  int w = threadIdx.x >> 6, lane = threadIdx.x & 63;
  int wm = w >> 1, wn = w & 1;
  int bid = blockIdx.x;
  int vid = (bid & 7) * 128 + (bid >> 3);
  int Mb = (vid >> 3) * 128, Nb = (vid & 7) * 128;
  int la = lane & 15, lk = (lane >> 4) * 8;
  f32x4 acc[4][4] = {};
  const f16* Ap[4]; const f16* Bp[4];
  for (int i = 0; i < 4; ++i){
    Ap[i] = Y  + (size_t)(Mb + wm*64 + i*16 + la) * HID;
    Bp[i] = Bt + (size_t)(Nb + wn*64 + i*16 + la) * HID;
  }
  #pragma unroll 2
  for (int k = 0; k < HID; k += 32){
    f16x8 af[4], bfr[4];
    for (int i = 0; i < 4; ++i){
      af[i]  = *reinterpret_cast<const f16x8*>(Ap[i] + k + lk);
      bfr[i] = *reinterpret_cast<const f16x8*>(Bp[i] + k + lk);
    }
    for (int mi = 0; mi < 4; ++mi)
      for (int ni = 0; ni < 4; ++ni)
        acc[mi][ni] = mfma16(af[mi], bfr[ni], acc[mi][ni]);
  }
  __shared__ float vs[2][64][2];
  float p[4][4];
  for (int mi = 0; mi < 4; ++mi) for (int i = 0; i < 4; ++i) p[mi][i] = 0.f;
  for (int ni = 0; ni < 4; ++ni){
    int col = Nb + wn*64 + ni*16 + la;
    float bb = b1[col], w2 = W2[col];
    for (int mi = 0; mi < 4; ++mi)
      for (int i = 0; i < 4; ++i){
        float c = acc[mi][ni][i] + bb;
        p[mi][i] += (c > 0.f ? c : 0.f) * w2;
      }
  }
  for (int mi = 0; mi < 4; ++mi) for (int i = 0; i < 4; ++i){
    float s = p[mi][i];
    s += __shfl_xor(s, 1); s += __shfl_xor(s, 2);
    s += __shfl_xor(s, 4); s += __shfl_xor(s, 8);
    p[mi][i] = s;
  }
  if (la == 0){
    int q = lane >> 4;
    for (int mi = 0; mi < 4; ++mi)
      for (int i = 0; i < 4; ++i)
        vs[wm][mi*16 + q*4 + i][wn] = p[mi][i];
  }
  __syncthreads();
  if (threadIdx.x < 128){
    int rw = threadIdx.x;
    float s = vs[rw >> 6][rw & 63][0] + vs[rw >> 6][rw & 63][1];
    vpart[(size_t)(Nb >> 7) * (TT*BB) + Mb + rw] = s;
  }
}

__global__ void k_vreduce(const float* __restrict__ vpart, const float* __restrict__ b2,
                          float* __restrict__ outv){
  int m = blockIdx.x * 256 + threadIdx.x;
  float s = b2[0];
  for (int nb = 0; nb < 8; ++nb) s += vpart[(size_t)nb * (TT*BB) + m];
  outv[m] = s;
}

extern "C" void kernel_launch(void* const* d_in, const int* in_sizes, int n_in,
                              void* d_out, int out_size, void* d_ws, size_t ws_size,
                              hipStream_t stream){
  const float* hidden = (const float*)d_in[0];
  const float* world  = (const float*)d_in[1];
  const int*   dones  = (const int*)d_in[2];
  const float* W_emb  = (const float*)d_in[3];
  const float* b_emb  = (const float*)d_in[4];
  const float* Wi     = (const float*)d_in[5];
  const float* bi     = (const float*)d_in[6];
  const float* Wh     = (const float*)d_in[7];
  const float* bhn    = (const float*)d_in[8];
  const float* W1     = (const float*)d_in[9];
  const float* b1     = (const float*)d_in[10];
  const float* W2     = (const float*)d_in[11];
  const float* b2     = (const float*)d_in[12];
  float* out = (float*)d_out;

  char* p = (char*)d_ws;
  auto alloc = [&](size_t bytes) -> char* {
    char* r = p; p += (bytes + 255) & ~(size_t)255; return r;
  };
  f16*   ws16   = (f16*)alloc((size_t)TT*BB*OBSD*2);     // 16 MB
  f16*   wembt  = (f16*)alloc((size_t)HID*OBSD*2);       // 1 MB
  f16*   emb16  = (f16*)alloc((size_t)TT*BB*HID*2);      // 33.5 MB
  f16*   bt2    = (f16*)alloc((size_t)3072*2048*2);      // 12.6 MB
  f16*   w1t    = (f16*)alloc((size_t)HID*HID*2);        // 2 MB
  f16*   ybuf   = (f16*)alloc((size_t)TT*BB*HID*2);      // 33.5 MB
  float* vpart  = (float*)alloc((size_t)8*TT*BB*4);      // 0.5 MB
  int*   off    = (int*)alloc((DPAR + 1) * 4);
  int*   rowlist= (int*)alloc((size_t)(TT*BB + 128)*4);  // 64 KB (+pad)
  int*   ntail  = (int*)alloc(4);
  int*   chains = (int*)alloc((size_t)700*3*4);
  if ((size_t)(p - (char*)d_ws) > ws_size) return;

  // preps (+ segmentation, depends only on dones)
  k_ws_to_f16<<<(TT*BB*OBSD/4 + 255)/256, 256, 0, stream>>>(world, ws16, TT*BB*OBSD/4);
  k_prep_bt<<<dim3(OBSD/64, HID/64), 256, 0, stream>>>(W_emb, 1024, wembt, OBSD);
  k_prep_bt2<<<dim3(2048/64, 3072/64), 256, 0, stream>>>(Wi, Wh, bt2);
  k_prep_bt<<<dim3(HID/64, HID/64), 256, 0, stream>>>(W1, 1024, w1t, HID);
  k_seg<<<1, 128, 0, stream>>>(dones, off, rowlist, ntail, chains);

  // embedding GEMM
  k_emb<<<1024, 256, 0, stream>>>(ws16, wembt, b_emb, emb16);

  // depth-parallel fused GRU scan: 24 launches + tail
  for (int j = 0; j < DPAR; ++j)
    k_depth<<<1024, 512, 0, stream>>>(j, off, rowlist, emb16, bt2, bi, bhn,
                                      dones, hidden, ybuf, out);
  k_tail<<<128, 256, 0, stream>>>(ntail, chains, emb16, bt2, bi, bhn, ybuf, out);

  // critic head + value
  k_critic<<<1024, 256, 0, stream>>>(ybuf, w1t, b1, W2, vpart);
  k_vreduce<<<TT*BB/256, 256, 0, stream>>>(vpart, b2, out + (size_t)BB*HID);
}